// Round 1
// baseline (808.143 us; speedup 1.0000x reference)
//
#include <hip/hip_runtime.h>

#define DD 128   // feature dim

// ---- degree count (atomic, float) ----
__global__ __launch_bounds__(256) void k_count(const int* __restrict__ dst,
                                               float* __restrict__ degc, int E, int N) {
    int e = blockIdx.x * 256 + threadIdx.x;
    if (e < E) {
        int d = dst[e];
        if ((unsigned)d < (unsigned)N) atomicAdd(&degc[d], 1.0f);
    }
}

__global__ __launch_bounds__(256) void k_dinv(const float* __restrict__ degc,
                                              float* __restrict__ dinv, int N) {
    int n = blockIdx.x * 256 + threadIdx.x;
    if (n < N) dinv[n] = rsqrtf(1.0f + degc[n]);
}

// ---- fold MHA (seq_len=1 => attn==1 => out = (h@Wv+bv)@Wo+bo) into one GEMM ----
__global__ __launch_bounds__(256) void k_fuse_w(const float* __restrict__ Wv, const float* __restrict__ Wo,
                                                const float* __restrict__ bv, const float* __restrict__ bo,
                                                float* __restrict__ Wf, float* __restrict__ bf) {
    int gid = blockIdx.x * 256 + threadIdx.x;
    if (gid >= (DD + 1) * DD) return;
    int i = gid >> 7, j = gid & (DD - 1);
    if (i < DD) {
        float acc = 0.f;
        for (int k = 0; k < DD; ++k) acc = fmaf(Wv[i * DD + k], Wo[k * DD + j], acc);
        Wf[i * DD + j] = acc;
    } else {
        float acc = bo[j];
        for (int k = 0; k < DD; ++k) acc = fmaf(bv[k], Wo[k * DD + j], acc);
        bf[j] = acc;
    }
}

// ---- C[M x 128] = A[M x 128] @ B[128 x 128] (+ optional bias) ----
// 256 threads/block, 32 rows/block, 4x4 register tile per thread.
// LDS = 64KB (B) + 16KB (A tile) = 80KB -> exactly 2 blocks/CU.
// Assumes M % 32 == 0 (N = 100000 = 3125*32).
__global__ __launch_bounds__(256) void k_gemm(const float* __restrict__ A, const float* __restrict__ B,
                                              const float* __restrict__ bias, float* __restrict__ C, int M) {
    __shared__ float Bs[DD][DD];
    __shared__ float As[32][DD];
    int t = threadIdx.x;
    #pragma unroll
    for (int i = 0; i < 16; ++i) {
        int idx = t + i * 256;   // float4 index, 4096 total
        reinterpret_cast<float4*>(&Bs[0][0])[idx] = reinterpret_cast<const float4*>(B)[idx];
    }
    size_t row0 = (size_t)blockIdx.x * 32;
    #pragma unroll
    for (int i = 0; i < 4; ++i) {
        int idx = t + i * 256;   // float4 index, 1024 total
        reinterpret_cast<float4*>(&As[0][0])[idx] =
            reinterpret_cast<const float4*>(A + row0 * DD)[idx];
    }
    __syncthreads();

    int tr = t >> 5, tc = t & 31;
    int r0 = tr * 4, c0 = tc * 4;
    float acc[4][4] = {};
    #pragma unroll 4
    for (int k = 0; k < DD; k += 4) {
        float4 a[4], w[4];
        #pragma unroll
        for (int i = 0; i < 4; ++i) a[i] = *reinterpret_cast<float4*>(&As[r0 + i][k]);
        #pragma unroll
        for (int kk = 0; kk < 4; ++kk) w[kk] = *reinterpret_cast<float4*>(&Bs[k + kk][c0]);
        #pragma unroll
        for (int i = 0; i < 4; ++i) {
            const float* ai = reinterpret_cast<const float*>(&a[i]);
            #pragma unroll
            for (int kk = 0; kk < 4; ++kk) {
                float av = ai[kk];
                const float* wk = reinterpret_cast<const float*>(&w[kk]);
                #pragma unroll
                for (int j = 0; j < 4; ++j)
                    acc[i][j] = fmaf(av, wk[j], acc[i][j]);
            }
        }
    }

    float4 bb = make_float4(0.f, 0.f, 0.f, 0.f);
    if (bias) bb = *reinterpret_cast<const float4*>(&bias[c0]);
    #pragma unroll
    for (int i = 0; i < 4; ++i) {
        float4 o;
        o.x = acc[i][0] + bb.x;
        o.y = acc[i][1] + bb.y;
        o.z = acc[i][2] + bb.z;
        o.w = acc[i][3] + bb.w;
        *reinterpret_cast<float4*>(&C[(row0 + r0 + i) * DD + c0]) = o;
    }
}

// ---- edge scatter: agg[dst] += h[src] * dinv[src]*dinv[dst], one thread per (e,d) ----
__global__ __launch_bounds__(256) void k_edge_scatter(const int* __restrict__ src, const int* __restrict__ dst,
                                                      const float* __restrict__ dinv, const float* __restrict__ h,
                                                      float* __restrict__ agg, int E, int N) {
    long long gid = (long long)blockIdx.x * 256 + threadIdx.x;
    int e = (int)(gid >> 7);
    int d = (int)(gid & (DD - 1));
    if (e >= E) return;
    int s = src[e], dd = dst[e];
    if ((unsigned)s >= (unsigned)N || (unsigned)dd >= (unsigned)N) return;
    float norm = dinv[s] * dinv[dd];
    atomicAdd(&agg[(size_t)dd * DD + d], h[(size_t)s * DD + d] * norm);
}

// ---- out = agg + h*dinv^2 + b, optional relu (in-place over agg allowed) ----
__global__ __launch_bounds__(256) void k_self_bias(const float* __restrict__ agg, const float* __restrict__ h,
                                                   const float* __restrict__ dinv, const float* __restrict__ b,
                                                   float* __restrict__ out, int N, int relu) {
    int gid = blockIdx.x * 256 + threadIdx.x;   // N*32 threads, float4 each
    int n = gid >> 5;
    if (n >= N) return;
    int d4 = (gid & 31) << 2;
    float di = dinv[n];
    float di2 = di * di;
    float4 a = *reinterpret_cast<const float4*>(&agg[(size_t)n * DD + d4]);
    float4 hh = *reinterpret_cast<const float4*>(&h[(size_t)n * DD + d4]);
    float4 bb = *reinterpret_cast<const float4*>(&b[d4]);
    float4 o;
    o.x = fmaf(hh.x, di2, a.x) + bb.x;
    o.y = fmaf(hh.y, di2, a.y) + bb.y;
    o.z = fmaf(hh.z, di2, a.z) + bb.z;
    o.w = fmaf(hh.w, di2, a.w) + bb.w;
    if (relu) {
        o.x = fmaxf(o.x, 0.f); o.y = fmaxf(o.y, 0.f);
        o.z = fmaxf(o.z, 0.f); o.w = fmaxf(o.w, 0.f);
    }
    *reinterpret_cast<float4*>(&out[(size_t)n * DD + d4]) = o;
}

extern "C" void kernel_launch(void* const* d_in, const int* in_sizes, int n_in,
                              void* d_out, int out_size, void* d_ws, size_t ws_size,
                              hipStream_t stream) {
    const float* x  = (const float*)d_in[0];
    const int*   ei = (const int*)d_in[1];
    const float* W1 = (const float*)d_in[2];
    const float* b1 = (const float*)d_in[3];
    const float* W2 = (const float*)d_in[4];
    const float* b2 = (const float*)d_in[5];
    // Wq/bq/Wk/bk (indices 6..9) are dead: softmax over seq_len=1 is identity.
    const float* Wv = (const float*)d_in[10];
    const float* bv = (const float*)d_in[11];
    const float* Wo = (const float*)d_in[12];
    const float* bo = (const float*)d_in[13];
    int N = in_sizes[0] / DD;
    int E = in_sizes[1] / 2;
    const int* src = ei;
    const int* dst = ei + E;
    float* out = (float*)d_out;

    float* bufA = (float*)d_ws;                 // N*D
    float* bufB = bufA + (size_t)N * DD;        // N*D
    float* degc = bufB + (size_t)N * DD;        // N
    float* dinv = degc + N;                     // N
    float* Wf   = dinv + N;                     // 128*128
    float* bf   = Wf + DD * DD;                 // 128

    hipMemsetAsync(degc, 0, (size_t)N * sizeof(float), stream);
    hipMemsetAsync(bufB, 0, (size_t)N * DD * sizeof(float), stream);

    k_count<<<(E + 255) / 256, 256, 0, stream>>>(dst, degc, E, N);
    k_dinv<<<(N + 255) / 256, 256, 0, stream>>>(degc, dinv, N);
    k_fuse_w<<<((DD + 1) * DD + 255) / 256, 256, 0, stream>>>(Wv, Wo, bv, bo, Wf, bf);

    int gemm_blocks = N / 32;                   // N divisible by 32
    int scat_blocks = (int)(((long long)E * DD + 255) / 256);
    int sb_blocks   = (N * 32 + 255) / 256;

    // layer 1
    k_gemm<<<gemm_blocks, 256, 0, stream>>>(x, W1, nullptr, bufA, N);
    k_edge_scatter<<<scat_blocks, 256, 0, stream>>>(src, dst, dinv, bufA, bufB, E, N);
    k_self_bias<<<sb_blocks, 256, 0, stream>>>(bufB, bufA, dinv, b1, bufB, N, 1);

    // layer 2
    k_gemm<<<gemm_blocks, 256, 0, stream>>>(bufB, W2, nullptr, bufA, N);
    hipMemsetAsync(bufB, 0, (size_t)N * DD * sizeof(float), stream);
    k_edge_scatter<<<scat_blocks, 256, 0, stream>>>(src, dst, dinv, bufA, bufB, E, N);
    k_self_bias<<<sb_blocks, 256, 0, stream>>>(bufB, bufA, dinv, b2, bufB, N, 0);

    // folded MHA
    k_gemm<<<gemm_blocks, 256, 0, stream>>>(bufB, Wf, bf, out, N);
}

// Round 3
// 397.107 us; speedup vs baseline: 2.0351x; 2.0351x over previous
//
#include <hip/hip_runtime.h>

#define DD 128   // feature dim

// ---- in-degree histogram (int atomics) ----
__global__ __launch_bounds__(256) void k_hist(const int* __restrict__ dst,
                                              int* __restrict__ cnt, int E, int N) {
    int e = blockIdx.x * 256 + threadIdx.x;
    if (e < E) {
        int d = dst[e];
        if ((unsigned)d < (unsigned)N) atomicAdd(&cnt[d], 1);
    }
}

__global__ __launch_bounds__(256) void k_dinv(const int* __restrict__ cnt,
                                              float* __restrict__ dinv, int N) {
    int n = blockIdx.x * 256 + threadIdx.x;
    if (n < N) dinv[n] = rsqrtf(1.0f + (float)cnt[n]);
}

// ---- exclusive scan of cnt[N] -> rowptr[N+1], 3-phase ----
__global__ __launch_bounds__(256) void k_scan_block(const int* __restrict__ cnt,
                                                    int* __restrict__ rowptr,
                                                    int* __restrict__ bsums, int N) {
    __shared__ int sh[256];
    int t = threadIdx.x;
    int gid = blockIdx.x * 256 + t;
    int v = (gid < N) ? cnt[gid] : 0;
    sh[t] = v;
    __syncthreads();
    #pragma unroll
    for (int off = 1; off < 256; off <<= 1) {
        int add = (t >= off) ? sh[t - off] : 0;
        __syncthreads();
        sh[t] += add;
        __syncthreads();
    }
    if (gid < N) rowptr[gid] = sh[t] - v;          // exclusive within block
    if (t == 255) bsums[blockIdx.x] = sh[255];     // block total
}

__global__ void k_scan_bsums(int* __restrict__ bsums, int nb) {
    if (threadIdx.x == 0 && blockIdx.x == 0) {
        int run = 0;
        for (int i = 0; i < nb; ++i) { int v = bsums[i]; bsums[i] = run; run += v; }
    }
}

__global__ __launch_bounds__(256) void k_scan_add(int* __restrict__ rowptr,
                                                  const int* __restrict__ bsums,
                                                  const int* __restrict__ cnt, int N) {
    int gid = blockIdx.x * 256 + threadIdx.x;
    if (gid < N) {
        int v = rowptr[gid] + bsums[gid >> 8];
        rowptr[gid] = v;
        if (gid == N - 1) rowptr[N] = v + cnt[gid];
    }
}

// ---- fill CSR buckets: srcs sorted by dst, with precomputed edge norm ----
__global__ __launch_bounds__(256) void k_fill(const int* __restrict__ src, const int* __restrict__ dst,
                                              const int* __restrict__ rowptr, int* __restrict__ fill,
                                              const float* __restrict__ dinv,
                                              int* __restrict__ srcs, float* __restrict__ normv,
                                              int E, int N) {
    int e = blockIdx.x * 256 + threadIdx.x;
    if (e >= E) return;
    int s = src[e], d = dst[e];
    if ((unsigned)s >= (unsigned)N || (unsigned)d >= (unsigned)N) return;
    int pos = rowptr[d] + atomicAdd(&fill[d], 1);
    srcs[pos] = s;
    normv[pos] = dinv[s] * dinv[d];
}

// ---- fold MHA (seq_len=1 => attn==1 => out = (h@Wv+bv)@Wo+bo) into one GEMM ----
__global__ __launch_bounds__(256) void k_fuse_w(const float* __restrict__ Wv, const float* __restrict__ Wo,
                                                const float* __restrict__ bv, const float* __restrict__ bo,
                                                float* __restrict__ Wf, float* __restrict__ bf) {
    int gid = blockIdx.x * 256 + threadIdx.x;
    if (gid >= (DD + 1) * DD) return;
    int i = gid >> 7, j = gid & (DD - 1);
    if (i < DD) {
        float acc = 0.f;
        for (int k = 0; k < DD; ++k) acc = fmaf(Wv[i * DD + k], Wo[k * DD + j], acc);
        Wf[i * DD + j] = acc;
    } else {
        float acc = bo[j];
        for (int k = 0; k < DD; ++k) acc = fmaf(bv[k], Wo[k * DD + j], acc);
        bf[j] = acc;
    }
}

// ---- C[M x 128] = A[M x 128] @ B[128 x 128] (+ optional bias) ----
__global__ __launch_bounds__(256) void k_gemm(const float* __restrict__ A, const float* __restrict__ B,
                                              const float* __restrict__ bias, float* __restrict__ C, int M) {
    __shared__ float Bs[DD][DD];
    __shared__ float As[32][DD];
    int t = threadIdx.x;
    #pragma unroll
    for (int i = 0; i < 16; ++i) {
        int idx = t + i * 256;
        reinterpret_cast<float4*>(&Bs[0][0])[idx] = reinterpret_cast<const float4*>(B)[idx];
    }
    size_t row0 = (size_t)blockIdx.x * 32;
    #pragma unroll
    for (int i = 0; i < 4; ++i) {
        int idx = t + i * 256;
        reinterpret_cast<float4*>(&As[0][0])[idx] =
            reinterpret_cast<const float4*>(A + row0 * DD)[idx];
    }
    __syncthreads();

    int tr = t >> 5, tc = t & 31;
    int r0 = tr * 4, c0 = tc * 4;
    float acc[4][4] = {};
    #pragma unroll 4
    for (int k = 0; k < DD; k += 4) {
        float4 a[4], w[4];
        #pragma unroll
        for (int i = 0; i < 4; ++i) a[i] = *reinterpret_cast<float4*>(&As[r0 + i][k]);
        #pragma unroll
        for (int kk = 0; kk < 4; ++kk) w[kk] = *reinterpret_cast<float4*>(&Bs[k + kk][c0]);
        #pragma unroll
        for (int i = 0; i < 4; ++i) {
            const float* ai = reinterpret_cast<const float*>(&a[i]);
            #pragma unroll
            for (int kk = 0; kk < 4; ++kk) {
                float av = ai[kk];
                const float* wk = reinterpret_cast<const float*>(&w[kk]);
                #pragma unroll
                for (int j = 0; j < 4; ++j)
                    acc[i][j] = fmaf(av, wk[j], acc[i][j]);
            }
        }
    }

    float4 bb = make_float4(0.f, 0.f, 0.f, 0.f);
    if (bias) bb = *reinterpret_cast<const float4*>(&bias[c0]);
    #pragma unroll
    for (int i = 0; i < 4; ++i) {
        float4 o;
        o.x = acc[i][0] + bb.x;
        o.y = acc[i][1] + bb.y;
        o.z = acc[i][2] + bb.z;
        o.w = acc[i][3] + bb.w;
        *reinterpret_cast<float4*>(&C[(row0 + r0 + i) * DD + c0]) = o;
    }
}

// ---- CSR gather + self-loop + bias (+relu): one wave per dst node ----
__global__ __launch_bounds__(256) void k_gather(const int* __restrict__ rowptr, const int* __restrict__ srcs,
                                                const float* __restrict__ normv, const float* __restrict__ h,
                                                const float* __restrict__ dinv, const float* __restrict__ bias,
                                                float* __restrict__ outp, int N, int relu) {
    int n = (blockIdx.x << 2) + (threadIdx.x >> 6);
    if (n >= N) return;
    int lane = threadIdx.x & 63;
    const float2* h2 = reinterpret_cast<const float2*>(h);
    int beg = rowptr[n], end = rowptr[n + 1];
    float ax = 0.f, ay = 0.f;
    int j = beg;
    for (; j + 1 < end; j += 2) {
        int s0 = srcs[j], s1 = srcs[j + 1];
        float w0 = normv[j], w1 = normv[j + 1];
        float2 a = h2[(size_t)s0 * 64 + lane];
        float2 b = h2[(size_t)s1 * 64 + lane];
        ax += w0 * a.x + w1 * b.x;
        ay += w0 * a.y + w1 * b.y;
    }
    if (j < end) {
        int s0 = srcs[j];
        float w0 = normv[j];
        float2 a = h2[(size_t)s0 * 64 + lane];
        ax += w0 * a.x;
        ay += w0 * a.y;
    }
    float di = dinv[n];
    float di2 = di * di;
    float2 self = h2[(size_t)n * 64 + lane];
    float2 bb = reinterpret_cast<const float2*>(bias)[lane];
    float ox = fmaf(self.x, di2, ax) + bb.x;
    float oy = fmaf(self.y, di2, ay) + bb.y;
    if (relu) { ox = fmaxf(ox, 0.f); oy = fmaxf(oy, 0.f); }
    reinterpret_cast<float2*>(outp)[(size_t)n * 64 + lane] = make_float2(ox, oy);
}

extern "C" void kernel_launch(void* const* d_in, const int* in_sizes, int n_in,
                              void* d_out, int out_size, void* d_ws, size_t ws_size,
                              hipStream_t stream) {
    const float* x  = (const float*)d_in[0];
    const int*   ei = (const int*)d_in[1];
    const float* W1 = (const float*)d_in[2];
    const float* b1 = (const float*)d_in[3];
    const float* W2 = (const float*)d_in[4];
    const float* b2 = (const float*)d_in[5];
    // Wq/bq/Wk/bk (indices 6..9) dead: softmax over seq_len=1 is identity.
    const float* Wv = (const float*)d_in[10];
    const float* bv = (const float*)d_in[11];
    const float* Wo = (const float*)d_in[12];
    const float* bo = (const float*)d_in[13];
    int N = in_sizes[0] / DD;
    int E = in_sizes[1] / 2;
    const int* src = ei;
    const int* dst = ei + E;
    float* out = (float*)d_out;

    float* bufA  = (float*)d_ws;                    // N*D
    float* bufB  = bufA + (size_t)N * DD;           // N*D
    float* dinv  = bufB + (size_t)N * DD;           // N
    float* normv = dinv + N;                        // E
    float* Wf    = normv + E;                       // 128*128
    float* bf    = Wf + DD * DD;                    // 128
    int*   cnt    = (int*)(bf + DD);                // N (also reused as fill ctr)
    int*   rowptr = cnt + N;                        // N+1
    int*   bsums  = rowptr + N + 1;                 // ~512
    int*   srcs   = bsums + 512;                    // E

    int nb = (N + 255) / 256;

    // ---- CSR build (shared by both GCN layers) ----
    hipMemsetAsync(cnt, 0, (size_t)N * sizeof(int), stream);
    k_hist<<<(E + 255) / 256, 256, 0, stream>>>(dst, cnt, E, N);
    k_dinv<<<nb, 256, 0, stream>>>(cnt, dinv, N);
    k_scan_block<<<nb, 256, 0, stream>>>(cnt, rowptr, bsums, N);
    k_scan_bsums<<<1, 64, 0, stream>>>(bsums, nb);
    k_scan_add<<<nb, 256, 0, stream>>>(rowptr, bsums, cnt, N);
    hipMemsetAsync(cnt, 0, (size_t)N * sizeof(int), stream);
    k_fill<<<(E + 255) / 256, 256, 0, stream>>>(src, dst, rowptr, cnt, dinv, srcs, normv, E, N);

    k_fuse_w<<<((DD + 1) * DD + 255) / 256, 256, 0, stream>>>(Wv, Wo, bv, bo, Wf, bf);

    int gemm_blocks = N / 32;                   // N divisible by 32
    int gat_blocks  = (N + 3) / 4;

    // layer 1
    k_gemm<<<gemm_blocks, 256, 0, stream>>>(x, W1, nullptr, bufA, N);
    k_gather<<<gat_blocks, 256, 0, stream>>>(rowptr, srcs, normv, bufA, dinv, b1, bufB, N, 1);

    // layer 2
    k_gemm<<<gemm_blocks, 256, 0, stream>>>(bufB, W2, nullptr, bufA, N);
    k_gather<<<gat_blocks, 256, 0, stream>>>(rowptr, srcs, normv, bufA, dinv, b2, bufB, N, 0);

    // folded MHA
    k_gemm<<<gemm_blocks, 256, 0, stream>>>(bufB, Wf, bf, out, N);
}

// Round 4
// 293.817 us; speedup vs baseline: 2.7505x; 1.3515x over previous
//
#include <hip/hip_runtime.h>
#include <hip/hip_bf16.h>

#define DD 128

typedef __bf16 bf16x8v __attribute__((ext_vector_type(8)));
typedef float  f32x4   __attribute__((ext_vector_type(4)));

__device__ inline unsigned short f2bf(float f) {
    unsigned u = __builtin_bit_cast(unsigned, f);
    unsigned r = (u + 0x7fffu + ((u >> 16) & 1u)) >> 16;
    return (unsigned short)r;
}
__device__ inline float bflo2f(unsigned p) { return __builtin_bit_cast(float, p << 16); }
__device__ inline float bfhi2f(unsigned p) { return __builtin_bit_cast(float, p & 0xffff0000u); }

// ---- in-degree histogram ----
__global__ __launch_bounds__(256) void k_hist(const int* __restrict__ dst,
                                              int* __restrict__ cnt, int E, int N) {
    int e = blockIdx.x * 256 + threadIdx.x;
    if (e < E) {
        int d = dst[e];
        if ((unsigned)d < (unsigned)N) atomicAdd(&cnt[d], 1);
    }
}

__global__ __launch_bounds__(256) void k_dinv(const int* __restrict__ cnt,
                                              float* __restrict__ dinv, int N) {
    int n = blockIdx.x * 256 + threadIdx.x;
    if (n < N) dinv[n] = rsqrtf(1.0f + (float)cnt[n]);
}

// ---- exclusive scan of cnt[N] -> rowptr[N+1] ----
__global__ __launch_bounds__(256) void k_scan_block(const int* __restrict__ cnt,
                                                    int* __restrict__ rowptr,
                                                    int* __restrict__ bsums, int N) {
    __shared__ int sh[256];
    int t = threadIdx.x;
    int gid = blockIdx.x * 256 + t;
    int v = (gid < N) ? cnt[gid] : 0;
    sh[t] = v;
    __syncthreads();
    #pragma unroll
    for (int off = 1; off < 256; off <<= 1) {
        int add = (t >= off) ? sh[t - off] : 0;
        __syncthreads();
        sh[t] += add;
        __syncthreads();
    }
    if (gid < N) rowptr[gid] = sh[t] - v;
    if (t == 255) bsums[blockIdx.x] = sh[255];
}

__global__ void k_scan_bsums(int* __restrict__ bsums, int nb) {
    if (threadIdx.x == 0 && blockIdx.x == 0) {
        int run = 0;
        for (int i = 0; i < nb; ++i) { int v = bsums[i]; bsums[i] = run; run += v; }
    }
}

__global__ __launch_bounds__(256) void k_scan_add(int* __restrict__ rowptr,
                                                  const int* __restrict__ bsums,
                                                  const int* __restrict__ cnt, int N) {
    int gid = blockIdx.x * 256 + threadIdx.x;
    if (gid < N) {
        int v = rowptr[gid] + bsums[gid >> 8];
        rowptr[gid] = v;
        if (gid == N - 1) rowptr[N] = v + cnt[gid];
    }
}

// ---- fill CSR: ev[pos] = (src, bits(norm)) grouped by dst ----
__global__ __launch_bounds__(256) void k_fill(const int* __restrict__ src, const int* __restrict__ dst,
                                              const int* __restrict__ rowptr, int* __restrict__ fill,
                                              const float* __restrict__ dinv,
                                              int2* __restrict__ ev, int E, int N) {
    int e = blockIdx.x * 256 + threadIdx.x;
    if (e >= E) return;
    int s = src[e], d = dst[e];
    if ((unsigned)s >= (unsigned)N || (unsigned)d >= (unsigned)N) return;
    int pos = rowptr[d] + atomicAdd(&fill[d], 1);
    float nm = dinv[s] * dinv[d];
    ev[pos] = make_int2(s, __builtin_bit_cast(int, nm));
}

// ---- fold MHA (seq_len=1 => attn==1): Wf = Wv@Wo, bf = bv@Wo + bo ----
__global__ __launch_bounds__(256) void k_fuse_w(const float* __restrict__ Wv, const float* __restrict__ Wo,
                                                const float* __restrict__ bv, const float* __restrict__ bo,
                                                float* __restrict__ Wf, float* __restrict__ bf) {
    int gid = blockIdx.x * 256 + threadIdx.x;
    if (gid >= (DD + 1) * DD) return;
    int i = gid >> 7, j = gid & (DD - 1);
    if (i < DD) {
        float acc = 0.f;
        for (int k = 0; k < DD; ++k) acc = fmaf(Wv[i * DD + k], Wo[k * DD + j], acc);
        Wf[i * DD + j] = acc;
    } else {
        float acc = bo[j];
        for (int k = 0; k < DD; ++k) acc = fmaf(bv[k], Wo[k * DD + j], acc);
        bf[j] = acc;
    }
}

// ---- transpose + cast W[k][n] f32 -> Wt[n][k] bf16 ----
__global__ __launch_bounds__(256) void k_prep(const float* __restrict__ W, unsigned short* __restrict__ Wt) {
    int gid = blockIdx.x * 256 + threadIdx.x;   // 16384
    int k = gid >> 7, n = gid & 127;
    Wt[n * DD + k] = f2bf(W[k * DD + n]);
}

// ---- MFMA GEMM: C[M x 128] = A[M x 128] @ Wt^T (+bias) ----
// Persistent blocks, 64 rows/tile, 4 waves x 16 rows. B fragments preloaded in
// registers (8 ntiles x 4 ksteps x bf16x8 = 128 VGPR); no LDS, no syncthreads.
// Layouts (m89/m91-verified): a/b frag: idx=l&15, k=(l>>4)*8+j; D: col=l&15, row=(l>>4)*4+reg.
template<int AF32, int OUTF32>
__global__ __launch_bounds__(256, 2) void k_gemm_mfma(const void* __restrict__ Av,
                                                      const unsigned short* __restrict__ Wt,
                                                      const float* __restrict__ bias,
                                                      void* __restrict__ Cv, int M) {
    int w  = threadIdx.x >> 6;
    int l  = threadIdx.x & 63;
    int lr = l & 15, lg = l >> 4;

    bf16x8v bfr[8][4];
    #pragma unroll
    for (int nt = 0; nt < 8; ++nt)
        #pragma unroll
        for (int kk = 0; kk < 4; ++kk)
            bfr[nt][kk] = *reinterpret_cast<const bf16x8v*>(Wt + (nt * 16 + lr) * DD + kk * 32 + lg * 8);

    float bvals[8];
    #pragma unroll
    for (int nt = 0; nt < 8; ++nt) bvals[nt] = bias ? bias[nt * 16 + lr] : 0.f;

    int tiles = (M + 63) >> 6;
    for (int t = blockIdx.x; t < tiles; t += gridDim.x) {
        int m0 = t * 64 + w * 16;
        int row = m0 + lr;
        int rowc = row < M ? row : (M - 1);

        bf16x8v af[4];
        if (AF32) {
            const float* Af = (const float*)Av;
            #pragma unroll
            for (int kk = 0; kk < 4; ++kk) {
                const float* p = Af + (size_t)rowc * DD + kk * 32 + lg * 8;
                float4 u0 = *reinterpret_cast<const float4*>(p);
                float4 u1 = *reinterpret_cast<const float4*>(p + 4);
                af[kk][0] = (__bf16)u0.x; af[kk][1] = (__bf16)u0.y;
                af[kk][2] = (__bf16)u0.z; af[kk][3] = (__bf16)u0.w;
                af[kk][4] = (__bf16)u1.x; af[kk][5] = (__bf16)u1.y;
                af[kk][6] = (__bf16)u1.z; af[kk][7] = (__bf16)u1.w;
            }
        } else {
            const unsigned short* Ab = (const unsigned short*)Av;
            #pragma unroll
            for (int kk = 0; kk < 4; ++kk)
                af[kk] = *reinterpret_cast<const bf16x8v*>(Ab + (size_t)rowc * DD + kk * 32 + lg * 8);
        }

        f32x4 acc[8] = {};
        #pragma unroll
        for (int kk = 0; kk < 4; ++kk)
            #pragma unroll
            for (int nt = 0; nt < 8; ++nt)
                acc[nt] = __builtin_amdgcn_mfma_f32_16x16x32_bf16(af[kk], bfr[nt][kk], acc[nt], 0, 0, 0);

        #pragma unroll
        for (int nt = 0; nt < 8; ++nt) {
            #pragma unroll
            for (int r = 0; r < 4; ++r) {
                int rr = m0 + lg * 4 + r;
                if (rr < M) {
                    float v = acc[nt][r] + bvals[nt];
                    if (OUTF32) ((float*)Cv)[(size_t)rr * DD + nt * 16 + lr] = v;
                    else ((unsigned short*)Cv)[(size_t)rr * DD + nt * 16 + lr] = f2bf(v);
                }
            }
        }
    }
}

// ---- CSR gather (bf16 h) + self-loop + bias (+relu) -> bf16 out ----
__global__ __launch_bounds__(256) void k_gather_bf(const int* __restrict__ rowptr, const int2* __restrict__ ev,
                                                   const unsigned short* __restrict__ h,
                                                   const float* __restrict__ dinv, const float* __restrict__ bias,
                                                   unsigned short* __restrict__ outp, int N, int relu) {
    int n = (blockIdx.x << 2) + (threadIdx.x >> 6);
    if (n >= N) return;
    int lane = threadIdx.x & 63;
    const unsigned* h32 = reinterpret_cast<const unsigned*>(h);   // 64 u32 per row
    int beg = rowptr[n], end = rowptr[n + 1];
    float ax = 0.f, ay = 0.f;
    int j = beg;
    for (; j + 1 < end; j += 2) {
        int2 e0 = ev[j], e1 = ev[j + 1];
        float w0 = __builtin_bit_cast(float, e0.y);
        float w1 = __builtin_bit_cast(float, e1.y);
        unsigned p0 = h32[(size_t)e0.x * 64 + lane];
        unsigned p1 = h32[(size_t)e1.x * 64 + lane];
        ax += w0 * bflo2f(p0) + w1 * bflo2f(p1);
        ay += w0 * bfhi2f(p0) + w1 * bfhi2f(p1);
    }
    if (j < end) {
        int2 e0 = ev[j];
        float w0 = __builtin_bit_cast(float, e0.y);
        unsigned p0 = h32[(size_t)e0.x * 64 + lane];
        ax += w0 * bflo2f(p0);
        ay += w0 * bfhi2f(p0);
    }
    float di = dinv[n];
    float di2 = di * di;
    unsigned ps = h32[(size_t)n * 64 + lane];
    float2 bb = reinterpret_cast<const float2*>(bias)[lane];
    float ox = fmaf(di2, bflo2f(ps), ax) + bb.x;
    float oy = fmaf(di2, bfhi2f(ps), ay) + bb.y;
    if (relu) { ox = fmaxf(ox, 0.f); oy = fmaxf(oy, 0.f); }
    unsigned po = (unsigned)f2bf(ox) | ((unsigned)f2bf(oy) << 16);
    reinterpret_cast<unsigned*>(outp)[(size_t)n * 64 + lane] = po;
}

extern "C" void kernel_launch(void* const* d_in, const int* in_sizes, int n_in,
                              void* d_out, int out_size, void* d_ws, size_t ws_size,
                              hipStream_t stream) {
    const float* x  = (const float*)d_in[0];
    const int*   ei = (const int*)d_in[1];
    const float* W1 = (const float*)d_in[2];
    const float* b1 = (const float*)d_in[3];
    const float* W2 = (const float*)d_in[4];
    const float* b2 = (const float*)d_in[5];
    // Wq/bq/Wk/bk (6..9) dead: softmax over seq_len=1 is identity.
    const float* Wv = (const float*)d_in[10];
    const float* bv = (const float*)d_in[11];
    const float* Wo = (const float*)d_in[12];
    const float* bo = (const float*)d_in[13];
    int N = in_sizes[0] / DD;
    int E = in_sizes[1] / 2;
    const int* src = ei;
    const int* dst = ei + E;
    float* out = (float*)d_out;

    unsigned short* hA = (unsigned short*)d_ws;       // N*128 bf16
    unsigned short* hB = hA + (size_t)N * DD;         // N*128 bf16
    float* dinv = (float*)(hB + (size_t)N * DD);      // N
    float* Wf   = dinv + N;                           // 128*128 f32
    float* bf   = Wf + DD * DD;                       // 128
    unsigned short* Wt1 = (unsigned short*)(bf + DD); // 128*128 bf16
    unsigned short* Wt2 = Wt1 + DD * DD;
    unsigned short* Wtf = Wt2 + DD * DD;
    int* cnt    = (int*)(Wtf + DD * DD);              // N
    int* rowptr = cnt + N;                            // N+1
    int* bsums  = rowptr + N + 1;                     // 512
    int2* ev    = (int2*)(((uintptr_t)(bsums + 512) + 15) & ~(uintptr_t)15);  // E

    int nb = (N + 255) / 256;

    // CSR build (shared by both layers)
    hipMemsetAsync(cnt, 0, (size_t)N * sizeof(int), stream);
    k_hist<<<(E + 255) / 256, 256, 0, stream>>>(dst, cnt, E, N);
    k_dinv<<<nb, 256, 0, stream>>>(cnt, dinv, N);
    k_scan_block<<<nb, 256, 0, stream>>>(cnt, rowptr, bsums, N);
    k_scan_bsums<<<1, 64, 0, stream>>>(bsums, nb);
    k_scan_add<<<nb, 256, 0, stream>>>(rowptr, bsums, cnt, N);
    hipMemsetAsync(cnt, 0, (size_t)N * sizeof(int), stream);
    k_fill<<<(E + 255) / 256, 256, 0, stream>>>(src, dst, rowptr, cnt, dinv, ev, E, N);

    // weight prep
    k_fuse_w<<<((DD + 1) * DD + 255) / 256, 256, 0, stream>>>(Wv, Wo, bv, bo, Wf, bf);
    k_prep<<<64, 256, 0, stream>>>(W1, Wt1);
    k_prep<<<64, 256, 0, stream>>>(W2, Wt2);
    k_prep<<<64, 256, 0, stream>>>(Wf, Wtf);

    int gat_blocks = (N + 3) / 4;

    // layer 1
    k_gemm_mfma<1, 0><<<512, 256, 0, stream>>>(x, Wt1, nullptr, hA, N);
    k_gather_bf<<<gat_blocks, 256, 0, stream>>>(rowptr, ev, hA, dinv, b1, hB, N, 1);

    // layer 2
    k_gemm_mfma<0, 0><<<512, 256, 0, stream>>>(hB, Wt2, nullptr, hA, N);
    k_gather_bf<<<gat_blocks, 256, 0, stream>>>(rowptr, ev, hA, dinv, b2, hB, N, 0);

    // folded MHA
    k_gemm_mfma<0, 1><<<512, 256, 0, stream>>>(hB, Wtf, bf, out, N);
}

// Round 5
// 255.905 us; speedup vs baseline: 3.1580x; 1.1481x over previous
//
#include <hip/hip_runtime.h>
#include <hip/hip_bf16.h>

#define DD 128

typedef __bf16 bf16x8v __attribute__((ext_vector_type(8)));
typedef float  f32x4   __attribute__((ext_vector_type(4)));

__device__ inline unsigned short f2bf(float f) {
    unsigned u = __builtin_bit_cast(unsigned, f);
    unsigned r = (u + 0x7fffu + ((u >> 16) & 1u)) >> 16;
    return (unsigned short)r;
}
__device__ inline float bflo2f(unsigned p) { return __builtin_bit_cast(float, p << 16); }
__device__ inline float bfhi2f(unsigned p) { return __builtin_bit_cast(float, p & 0xffff0000u); }
__device__ inline float rl_f(int v, int i) {
    return __builtin_bit_cast(float, __builtin_amdgcn_readlane(v, i));
}

// ---- in-degree histogram ----
__global__ __launch_bounds__(256) void k_hist(const int* __restrict__ dst,
                                              int* __restrict__ cnt, int E, int N) {
    int e = blockIdx.x * 256 + threadIdx.x;
    if (e < E) {
        int d = dst[e];
        if ((unsigned)d < (unsigned)N) atomicAdd(&cnt[d], 1);
    }
}

// ---- exclusive scan of cnt[N] -> rowptr[N+1] ----
__global__ __launch_bounds__(256) void k_scan_block(const int* __restrict__ cnt,
                                                    int* __restrict__ rowptr,
                                                    int* __restrict__ bsums, int N) {
    __shared__ int sh[256];
    int t = threadIdx.x;
    int gid = blockIdx.x * 256 + t;
    int v = (gid < N) ? cnt[gid] : 0;
    sh[t] = v;
    __syncthreads();
    #pragma unroll
    for (int off = 1; off < 256; off <<= 1) {
        int add = (t >= off) ? sh[t - off] : 0;
        __syncthreads();
        sh[t] += add;
        __syncthreads();
    }
    if (gid < N) rowptr[gid] = sh[t] - v;
    if (t == 255) bsums[blockIdx.x] = sh[255];
}

__global__ void k_scan_bsums(int* __restrict__ bsums, int nb) {
    if (threadIdx.x == 0 && blockIdx.x == 0) {
        int run = 0;
        for (int i = 0; i < nb; ++i) { int v = bsums[i]; bsums[i] = run; run += v; }
    }
}

// ---- scan finalize + dinv fused ----
__global__ __launch_bounds__(256) void k_scan_add(int* __restrict__ rowptr,
                                                  const int* __restrict__ bsums,
                                                  const int* __restrict__ cnt,
                                                  float* __restrict__ dinv, int N) {
    int gid = blockIdx.x * 256 + threadIdx.x;
    if (gid < N) {
        int v = rowptr[gid] + bsums[gid >> 8];
        rowptr[gid] = v;
        if (gid == N - 1) rowptr[N] = v + cnt[gid];
        dinv[gid] = rsqrtf(1.0f + (float)cnt[gid]);
    }
}

// ---- fill CSR: ev[pos] = (src, bits(norm)) grouped by dst ----
__global__ __launch_bounds__(256) void k_fill(const int* __restrict__ src, const int* __restrict__ dst,
                                              const int* __restrict__ rowptr, int* __restrict__ fill,
                                              const float* __restrict__ dinv,
                                              int2* __restrict__ ev, int E, int N) {
    int e = blockIdx.x * 256 + threadIdx.x;
    if (e >= E) return;
    int s = src[e], d = dst[e];
    if ((unsigned)s >= (unsigned)N || (unsigned)d >= (unsigned)N) return;
    int pos = rowptr[d] + atomicAdd(&fill[d], 1);
    float nm = dinv[s] * dinv[d];
    ev[pos] = make_int2(s, __builtin_bit_cast(int, nm));
}

// ---- fold MHA: Wtf[j][i] = bf16(sum_k Wv[i][k] Wo[k][j]), bf = bv@Wo + bo ----
__global__ __launch_bounds__(256) void k_fuse_w(const float* __restrict__ Wv, const float* __restrict__ Wo,
                                                const float* __restrict__ bv, const float* __restrict__ bo,
                                                unsigned short* __restrict__ Wtf, float* __restrict__ bf) {
    int gid = blockIdx.x * 256 + threadIdx.x;
    if (gid >= (DD + 1) * DD) return;
    int i = gid >> 7, j = gid & (DD - 1);
    if (i < DD) {
        float acc = 0.f;
        for (int k = 0; k < DD; ++k) acc = fmaf(Wv[i * DD + k], Wo[k * DD + j], acc);
        Wtf[j * DD + i] = f2bf(acc);   // transposed bf16 directly
    } else {
        float acc = bo[j];
        for (int k = 0; k < DD; ++k) acc = fmaf(bv[k], Wo[k * DD + j], acc);
        bf[j] = acc;
    }
}

// ---- transpose + cast W[k][n] f32 -> Wt[n][k] bf16 ----
__global__ __launch_bounds__(256) void k_prep(const float* __restrict__ W, unsigned short* __restrict__ Wt) {
    int gid = blockIdx.x * 256 + threadIdx.x;   // 16384
    int k = gid >> 7, n = gid & 127;
    Wt[n * DD + k] = f2bf(W[k * DD + n]);
}

// ---- MFMA GEMM: C[M x 128] = A[M x 128] @ Wt^T (+bias) ----
// Persistent blocks, 64 rows/tile, 4 waves x 16 rows. B fragments preloaded in
// registers; no LDS, no syncthreads.
// Layouts (m89/m91): a/b frag: idx=l&15, k=(l>>4)*8+j; D: col=l&15, row=(l>>4)*4+reg.
template<int AF32, int OUTF32>
__global__ __launch_bounds__(256, 2) void k_gemm_mfma(const void* __restrict__ Av,
                                                      const unsigned short* __restrict__ Wt,
                                                      const float* __restrict__ bias,
                                                      void* __restrict__ Cv, int M) {
    int w  = threadIdx.x >> 6;
    int l  = threadIdx.x & 63;
    int lr = l & 15, lg = l >> 4;

    bf16x8v bfr[8][4];
    #pragma unroll
    for (int nt = 0; nt < 8; ++nt)
        #pragma unroll
        for (int kk = 0; kk < 4; ++kk)
            bfr[nt][kk] = *reinterpret_cast<const bf16x8v*>(Wt + (nt * 16 + lr) * DD + kk * 32 + lg * 8);

    float bvals[8];
    #pragma unroll
    for (int nt = 0; nt < 8; ++nt) bvals[nt] = bias ? bias[nt * 16 + lr] : 0.f;

    int tiles = (M + 63) >> 6;
    for (int t = blockIdx.x; t < tiles; t += gridDim.x) {
        int m0 = t * 64 + w * 16;
        int row = m0 + lr;
        int rowc = row < M ? row : (M - 1);

        bf16x8v af[4];
        if (AF32) {
            const float* Af = (const float*)Av;
            #pragma unroll
            for (int kk = 0; kk < 4; ++kk) {
                const float* p = Af + (size_t)rowc * DD + kk * 32 + lg * 8;
                float4 u0 = *reinterpret_cast<const float4*>(p);
                float4 u1 = *reinterpret_cast<const float4*>(p + 4);
                af[kk][0] = (__bf16)u0.x; af[kk][1] = (__bf16)u0.y;
                af[kk][2] = (__bf16)u0.z; af[kk][3] = (__bf16)u0.w;
                af[kk][4] = (__bf16)u1.x; af[kk][5] = (__bf16)u1.y;
                af[kk][6] = (__bf16)u1.z; af[kk][7] = (__bf16)u1.w;
            }
        } else {
            const unsigned short* Ab = (const unsigned short*)Av;
            #pragma unroll
            for (int kk = 0; kk < 4; ++kk)
                af[kk] = *reinterpret_cast<const bf16x8v*>(Ab + (size_t)rowc * DD + kk * 32 + lg * 8);
        }

        f32x4 acc[8] = {};
        #pragma unroll
        for (int kk = 0; kk < 4; ++kk)
            #pragma unroll
            for (int nt = 0; nt < 8; ++nt)
                acc[nt] = __builtin_amdgcn_mfma_f32_16x16x32_bf16(af[kk], bfr[nt][kk], acc[nt], 0, 0, 0);

        #pragma unroll
        for (int nt = 0; nt < 8; ++nt) {
            #pragma unroll
            for (int r = 0; r < 4; ++r) {
                int rr = m0 + lg * 4 + r;
                if (rr < M) {
                    float v = acc[nt][r] + bvals[nt];
                    if (OUTF32) ((float*)Cv)[(size_t)rr * DD + nt * 16 + lr] = v;
                    else ((unsigned short*)Cv)[(size_t)rr * DD + nt * 16 + lr] = f2bf(v);
                }
            }
        }
    }
}

// ---- CSR gather v2: persistent waves, edge-list broadcast via readlane ----
__global__ __launch_bounds__(256) void k_gather_bf(const int* __restrict__ rowptr, const int2* __restrict__ ev,
                                                   const unsigned short* __restrict__ h,
                                                   const float* __restrict__ dinv, const float* __restrict__ bias,
                                                   unsigned short* __restrict__ outp, int N, int relu) {
    int lane = threadIdx.x & 63;
    int wid  = blockIdx.x * 4 + (threadIdx.x >> 6);
    int nw   = gridDim.x * 4;
    const unsigned* h32 = reinterpret_cast<const unsigned*>(h);
    float2 bb = reinterpret_cast<const float2*>(bias)[lane];

    for (int n = wid; n < N; n += nw) {
        int beg = rowptr[n], end = rowptr[n + 1];
        int deg = end - beg;
        float ax = 0.f, ay = 0.f;

        for (int base = 0; base < deg; base += 64) {
            int cnt = deg - base; if (cnt > 64) cnt = 64;
            int2 me = ev[beg + base + (lane < cnt ? lane : cnt - 1)];
            int i = 0;
            for (; i + 4 <= cnt; i += 4) {
                int s0 = __builtin_amdgcn_readlane(me.x, i);
                int s1 = __builtin_amdgcn_readlane(me.x, i + 1);
                int s2 = __builtin_amdgcn_readlane(me.x, i + 2);
                int s3 = __builtin_amdgcn_readlane(me.x, i + 3);
                unsigned p0 = h32[(size_t)s0 * 64 + lane];
                unsigned p1 = h32[(size_t)s1 * 64 + lane];
                unsigned p2 = h32[(size_t)s2 * 64 + lane];
                unsigned p3 = h32[(size_t)s3 * 64 + lane];
                float w0 = rl_f(me.y, i);
                float w1 = rl_f(me.y, i + 1);
                float w2 = rl_f(me.y, i + 2);
                float w3 = rl_f(me.y, i + 3);
                ax += w0 * bflo2f(p0) + w1 * bflo2f(p1) + w2 * bflo2f(p2) + w3 * bflo2f(p3);
                ay += w0 * bfhi2f(p0) + w1 * bfhi2f(p1) + w2 * bfhi2f(p2) + w3 * bfhi2f(p3);
            }
            for (; i < cnt; ++i) {
                int s0 = __builtin_amdgcn_readlane(me.x, i);
                unsigned p0 = h32[(size_t)s0 * 64 + lane];
                float w0 = rl_f(me.y, i);
                ax += w0 * bflo2f(p0);
                ay += w0 * bfhi2f(p0);
            }
        }

        float di = dinv[n];
        float di2 = di * di;
        unsigned ps = h32[(size_t)n * 64 + lane];
        float ox = fmaf(di2, bflo2f(ps), ax) + bb.x;
        float oy = fmaf(di2, bfhi2f(ps), ay) + bb.y;
        if (relu) { ox = fmaxf(ox, 0.f); oy = fmaxf(oy, 0.f); }
        unsigned po = (unsigned)f2bf(ox) | ((unsigned)f2bf(oy) << 16);
        reinterpret_cast<unsigned*>(outp)[(size_t)n * 64 + lane] = po;
    }
}

extern "C" void kernel_launch(void* const* d_in, const int* in_sizes, int n_in,
                              void* d_out, int out_size, void* d_ws, size_t ws_size,
                              hipStream_t stream) {
    const float* x  = (const float*)d_in[0];
    const int*   ei = (const int*)d_in[1];
    const float* W1 = (const float*)d_in[2];
    const float* b1 = (const float*)d_in[3];
    const float* W2 = (const float*)d_in[4];
    const float* b2 = (const float*)d_in[5];
    // Wq/bq/Wk/bk (6..9) dead: softmax over seq_len=1 is identity.
    const float* Wv = (const float*)d_in[10];
    const float* bv = (const float*)d_in[11];
    const float* Wo = (const float*)d_in[12];
    const float* bo = (const float*)d_in[13];
    int N = in_sizes[0] / DD;
    int E = in_sizes[1] / 2;
    const int* src = ei;
    const int* dst = ei + E;
    float* out = (float*)d_out;

    unsigned short* hA = (unsigned short*)d_ws;       // N*128 bf16
    unsigned short* hB = hA + (size_t)N * DD;         // N*128 bf16
    float* dinv = (float*)(hB + (size_t)N * DD);      // N
    float* bf   = dinv + N;                           // 128
    unsigned short* Wt1 = (unsigned short*)(bf + DD); // 128*128 bf16
    unsigned short* Wt2 = Wt1 + DD * DD;
    unsigned short* Wtf = Wt2 + DD * DD;
    int* cnt    = (int*)(Wtf + DD * DD);              // N
    int* rowptr = cnt + N;                            // N+1
    int* bsums  = rowptr + N + 1;                     // 512
    int2* ev    = (int2*)(((uintptr_t)(bsums + 512) + 15) & ~(uintptr_t)15);  // E

    int nb = (N + 255) / 256;

    // CSR build (shared by both layers)
    hipMemsetAsync(cnt, 0, (size_t)N * sizeof(int), stream);
    k_hist<<<(E + 255) / 256, 256, 0, stream>>>(dst, cnt, E, N);
    k_scan_block<<<nb, 256, 0, stream>>>(cnt, rowptr, bsums, N);
    k_scan_bsums<<<1, 64, 0, stream>>>(bsums, nb);
    k_scan_add<<<nb, 256, 0, stream>>>(rowptr, bsums, cnt, dinv, N);
    hipMemsetAsync(cnt, 0, (size_t)N * sizeof(int), stream);
    k_fill<<<(E + 255) / 256, 256, 0, stream>>>(src, dst, rowptr, cnt, dinv, ev, E, N);

    // weight prep
    k_fuse_w<<<((DD + 1) * DD + 255) / 256, 256, 0, stream>>>(Wv, Wo, bv, bo, Wtf, bf);
    k_prep<<<64, 256, 0, stream>>>(W1, Wt1);
    k_prep<<<64, 256, 0, stream>>>(W2, Wt2);

    // layer 1
    k_gemm_mfma<1, 0><<<512, 256, 0, stream>>>(x, Wt1, nullptr, hA, N);
    k_gather_bf<<<2048, 256, 0, stream>>>(rowptr, ev, hA, dinv, b1, hB, N, 1);

    // layer 2
    k_gemm_mfma<0, 0><<<512, 256, 0, stream>>>(hB, Wt2, nullptr, hA, N);
    k_gather_bf<<<2048, 256, 0, stream>>>(rowptr, ev, hA, dinv, b2, hB, N, 0);

    // folded MHA
    k_gemm_mfma<0, 1><<<512, 256, 0, stream>>>(hB, Wtf, bf, out, N);
}

// Round 6
// 215.895 us; speedup vs baseline: 3.7432x; 1.1853x over previous
//
#include <hip/hip_runtime.h>
#include <hip/hip_bf16.h>

#define DD 128

typedef __bf16 bf16x8v __attribute__((ext_vector_type(8)));
typedef float  f32x4   __attribute__((ext_vector_type(4)));

__device__ inline unsigned short f2bf(float f) {
    unsigned u = __builtin_bit_cast(unsigned, f);
    unsigned r = (u + 0x7fffu + ((u >> 16) & 1u)) >> 16;
    return (unsigned short)r;
}
__device__ inline float bflo2f(unsigned p) { return __builtin_bit_cast(float, p << 16); }
__device__ inline float bfhi2f(unsigned p) { return __builtin_bit_cast(float, p & 0xffff0000u); }
__device__ inline float rl_f(int v, int i) {
    return __builtin_bit_cast(float, __builtin_amdgcn_readlane(v, i));
}

// ---- in-degree histogram ----
__global__ __launch_bounds__(256) void k_hist(const int* __restrict__ dst,
                                              int* __restrict__ cnt, int E, int N) {
    int e = blockIdx.x * 256 + threadIdx.x;
    if (e < E) {
        int d = dst[e];
        if ((unsigned)d < (unsigned)N) atomicAdd(&cnt[d], 1);
    }
}

// ---- exclusive scan of cnt[N] -> rowptr[N+1] ----
__global__ __launch_bounds__(256) void k_scan_block(const int* __restrict__ cnt,
                                                    int* __restrict__ rowptr,
                                                    int* __restrict__ bsums, int N) {
    __shared__ int sh[256];
    int t = threadIdx.x;
    int gid = blockIdx.x * 256 + t;
    int v = (gid < N) ? cnt[gid] : 0;
    sh[t] = v;
    __syncthreads();
    #pragma unroll
    for (int off = 1; off < 256; off <<= 1) {
        int add = (t >= off) ? sh[t - off] : 0;
        __syncthreads();
        sh[t] += add;
        __syncthreads();
    }
    if (gid < N) rowptr[gid] = sh[t] - v;
    if (t == 255) bsums[blockIdx.x] = sh[255];
}

// ---- parallel single-block scan of block sums (nb <= 512) ----
__global__ __launch_bounds__(256) void k_scan_bsums(int* __restrict__ bsums, int nb) {
    __shared__ int sh[512];
    int t = threadIdx.x;
    sh[t]       = (t < nb)       ? bsums[t]       : 0;
    sh[t + 256] = (t + 256 < nb) ? bsums[t + 256] : 0;
    __syncthreads();
    #pragma unroll
    for (int off = 1; off < 512; off <<= 1) {
        int a = (t >= off)       ? sh[t - off]       : 0;
        int b = (t + 256 >= off) ? sh[t + 256 - off] : 0;
        __syncthreads();
        sh[t] += a;
        sh[t + 256] += b;
        __syncthreads();
    }
    // write exclusive scan back
    if (t < nb)       bsums[t]       = (t == 0) ? 0 : sh[t - 1];
    if (t + 256 < nb) bsums[t + 256] = sh[t + 255];
}

// ---- scan finalize + dinv fused ----
__global__ __launch_bounds__(256) void k_scan_add(int* __restrict__ rowptr,
                                                  const int* __restrict__ bsums,
                                                  const int* __restrict__ cnt,
                                                  float* __restrict__ dinv, int N) {
    int gid = blockIdx.x * 256 + threadIdx.x;
    if (gid < N) {
        int v = rowptr[gid] + bsums[gid >> 8];
        rowptr[gid] = v;
        if (gid == N - 1) rowptr[N] = v + cnt[gid];
        dinv[gid] = rsqrtf(1.0f + (float)cnt[gid]);
    }
}

// ---- fill CSR: ev[pos] = (src, bits(norm)) grouped by dst ----
__global__ __launch_bounds__(256) void k_fill(const int* __restrict__ src, const int* __restrict__ dst,
                                              const int* __restrict__ rowptr, int* __restrict__ fill,
                                              const float* __restrict__ dinv,
                                              int2* __restrict__ ev, int E, int N) {
    int e = blockIdx.x * 256 + threadIdx.x;
    if (e >= E) return;
    int s = src[e], d = dst[e];
    if ((unsigned)s >= (unsigned)N || (unsigned)d >= (unsigned)N) return;
    int pos = rowptr[d] + atomicAdd(&fill[d], 1);
    float nm = dinv[s] * dinv[d];
    ev[pos] = make_int2(s, __builtin_bit_cast(int, nm));
}

// ---- fold MHA: Wtf[j][i] = bf16(sum_k Wv[i][k] Wo[k][j]), bf = bv@Wo + bo ----
__global__ __launch_bounds__(256) void k_fuse_w(const float* __restrict__ Wv, const float* __restrict__ Wo,
                                                const float* __restrict__ bv, const float* __restrict__ bo,
                                                unsigned short* __restrict__ Wtf, float* __restrict__ bf) {
    int gid = blockIdx.x * 256 + threadIdx.x;
    if (gid >= (DD + 1) * DD) return;
    int i = gid >> 7, j = gid & (DD - 1);
    if (i < DD) {
        float acc = 0.f;
        for (int k = 0; k < DD; ++k) acc = fmaf(Wv[i * DD + k], Wo[k * DD + j], acc);
        Wtf[j * DD + i] = f2bf(acc);   // transposed bf16 directly
    } else {
        float acc = bo[j];
        for (int k = 0; k < DD; ++k) acc = fmaf(bv[k], Wo[k * DD + j], acc);
        bf[j] = acc;
    }
}

// ---- transpose + cast W[k][n] f32 -> Wt[n][k] bf16 ----
__global__ __launch_bounds__(256) void k_prep(const float* __restrict__ W, unsigned short* __restrict__ Wt) {
    int gid = blockIdx.x * 256 + threadIdx.x;   // 16384
    int k = gid >> 7, n = gid & 127;
    Wt[n * DD + k] = f2bf(W[k * DD + n]);
}

// ---- MFMA GEMM: C[M x 128] = A[M x 128] @ Wt^T (+bias) ----
// Persistent blocks, 64 rows/tile, 4 waves x 16 rows. B fragments preloaded in
// registers; no LDS, no syncthreads.
// Layouts (m89/m91): a/b frag: idx=l&15, k=(l>>4)*8+j; D: col=l&15, row=(l>>4)*4+reg.
template<int AF32, int OUTF32>
__global__ __launch_bounds__(256, 2) void k_gemm_mfma(const void* __restrict__ Av,
                                                      const unsigned short* __restrict__ Wt,
                                                      const float* __restrict__ bias,
                                                      void* __restrict__ Cv, int M) {
    int w  = threadIdx.x >> 6;
    int l  = threadIdx.x & 63;
    int lr = l & 15, lg = l >> 4;

    bf16x8v bfr[8][4];
    #pragma unroll
    for (int nt = 0; nt < 8; ++nt)
        #pragma unroll
        for (int kk = 0; kk < 4; ++kk)
            bfr[nt][kk] = *reinterpret_cast<const bf16x8v*>(Wt + (nt * 16 + lr) * DD + kk * 32 + lg * 8);

    float bvals[8];
    #pragma unroll
    for (int nt = 0; nt < 8; ++nt) bvals[nt] = bias ? bias[nt * 16 + lr] : 0.f;

    int tiles = (M + 63) >> 6;
    for (int t = blockIdx.x; t < tiles; t += gridDim.x) {
        int m0 = t * 64 + w * 16;
        int row = m0 + lr;
        int rowc = row < M ? row : (M - 1);

        bf16x8v af[4];
        if (AF32) {
            const float* Af = (const float*)Av;
            #pragma unroll
            for (int kk = 0; kk < 4; ++kk) {
                const float* p = Af + (size_t)rowc * DD + kk * 32 + lg * 8;
                float4 u0 = *reinterpret_cast<const float4*>(p);
                float4 u1 = *reinterpret_cast<const float4*>(p + 4);
                af[kk][0] = (__bf16)u0.x; af[kk][1] = (__bf16)u0.y;
                af[kk][2] = (__bf16)u0.z; af[kk][3] = (__bf16)u0.w;
                af[kk][4] = (__bf16)u1.x; af[kk][5] = (__bf16)u1.y;
                af[kk][6] = (__bf16)u1.z; af[kk][7] = (__bf16)u1.w;
            }
        } else {
            const unsigned short* Ab = (const unsigned short*)Av;
            #pragma unroll
            for (int kk = 0; kk < 4; ++kk)
                af[kk] = *reinterpret_cast<const bf16x8v*>(Ab + (size_t)rowc * DD + kk * 32 + lg * 8);
        }

        f32x4 acc[8] = {};
        #pragma unroll
        for (int kk = 0; kk < 4; ++kk)
            #pragma unroll
            for (int nt = 0; nt < 8; ++nt)
                acc[nt] = __builtin_amdgcn_mfma_f32_16x16x32_bf16(af[kk], bfr[nt][kk], acc[nt], 0, 0, 0);

        #pragma unroll
        for (int nt = 0; nt < 8; ++nt) {
            #pragma unroll
            for (int r = 0; r < 4; ++r) {
                int rr = m0 + lg * 4 + r;
                if (rr < M) {
                    float v = acc[nt][r] + bvals[nt];
                    if (OUTF32) ((float*)Cv)[(size_t)rr * DD + nt * 16 + lr] = v;
                    else ((unsigned short*)Cv)[(size_t)rr * DD + nt * 16 + lr] = f2bf(v);
                }
            }
        }
    }
}

// ---- CSR gather: persistent waves, edge-list broadcast via readlane ----
__global__ __launch_bounds__(256) void k_gather_bf(const int* __restrict__ rowptr, const int2* __restrict__ ev,
                                                   const unsigned short* __restrict__ h,
                                                   const float* __restrict__ dinv, const float* __restrict__ bias,
                                                   unsigned short* __restrict__ outp, int N, int relu) {
    int lane = threadIdx.x & 63;
    int wid  = blockIdx.x * 4 + (threadIdx.x >> 6);
    int nw   = gridDim.x * 4;
    const unsigned* h32 = reinterpret_cast<const unsigned*>(h);
    float2 bb = reinterpret_cast<const float2*>(bias)[lane];

    for (int n = wid; n < N; n += nw) {
        int beg = rowptr[n], end = rowptr[n + 1];
        int deg = end - beg;
        float ax = 0.f, ay = 0.f;

        for (int base = 0; base < deg; base += 64) {
            int cnt = deg - base; if (cnt > 64) cnt = 64;
            int2 me = ev[beg + base + (lane < cnt ? lane : cnt - 1)];
            int i = 0;
            for (; i + 4 <= cnt; i += 4) {
                int s0 = __builtin_amdgcn_readlane(me.x, i);
                int s1 = __builtin_amdgcn_readlane(me.x, i + 1);
                int s2 = __builtin_amdgcn_readlane(me.x, i + 2);
                int s3 = __builtin_amdgcn_readlane(me.x, i + 3);
                unsigned p0 = h32[(size_t)s0 * 64 + lane];
                unsigned p1 = h32[(size_t)s1 * 64 + lane];
                unsigned p2 = h32[(size_t)s2 * 64 + lane];
                unsigned p3 = h32[(size_t)s3 * 64 + lane];
                float w0 = rl_f(me.y, i);
                float w1 = rl_f(me.y, i + 1);
                float w2 = rl_f(me.y, i + 2);
                float w3 = rl_f(me.y, i + 3);
                ax += w0 * bflo2f(p0) + w1 * bflo2f(p1) + w2 * bflo2f(p2) + w3 * bflo2f(p3);
                ay += w0 * bfhi2f(p0) + w1 * bfhi2f(p1) + w2 * bfhi2f(p2) + w3 * bfhi2f(p3);
            }
            for (; i < cnt; ++i) {
                int s0 = __builtin_amdgcn_readlane(me.x, i);
                unsigned p0 = h32[(size_t)s0 * 64 + lane];
                float w0 = rl_f(me.y, i);
                ax += w0 * bflo2f(p0);
                ay += w0 * bfhi2f(p0);
            }
        }

        float di = dinv[n];
        float di2 = di * di;
        unsigned ps = h32[(size_t)n * 64 + lane];
        float ox = fmaf(di2, bflo2f(ps), ax) + bb.x;
        float oy = fmaf(di2, bfhi2f(ps), ay) + bb.y;
        if (relu) { ox = fmaxf(ox, 0.f); oy = fmaxf(oy, 0.f); }
        unsigned po = (unsigned)f2bf(ox) | ((unsigned)f2bf(oy) << 16);
        reinterpret_cast<unsigned*>(outp)[(size_t)n * 64 + lane] = po;
    }
}

extern "C" void kernel_launch(void* const* d_in, const int* in_sizes, int n_in,
                              void* d_out, int out_size, void* d_ws, size_t ws_size,
                              hipStream_t stream) {
    const float* x  = (const float*)d_in[0];
    const int*   ei = (const int*)d_in[1];
    const float* W1 = (const float*)d_in[2];
    const float* b1 = (const float*)d_in[3];
    const float* W2 = (const float*)d_in[4];
    const float* b2 = (const float*)d_in[5];
    // Wq/bq/Wk/bk (6..9) dead: softmax over seq_len=1 is identity.
    const float* Wv = (const float*)d_in[10];
    const float* bv = (const float*)d_in[11];
    const float* Wo = (const float*)d_in[12];
    const float* bo = (const float*)d_in[13];
    int N = in_sizes[0] / DD;
    int E = in_sizes[1] / 2;
    const int* src = ei;
    const int* dst = ei + E;
    float* out = (float*)d_out;

    unsigned short* hA = (unsigned short*)d_ws;       // N*128 bf16
    unsigned short* hB = hA + (size_t)N * DD;         // N*128 bf16
    float* dinv = (float*)(hB + (size_t)N * DD);      // N
    float* bf   = dinv + N;                           // 128
    unsigned short* Wt1 = (unsigned short*)(bf + DD); // 128*128 bf16
    unsigned short* Wt2 = Wt1 + DD * DD;
    unsigned short* Wtf = Wt2 + DD * DD;
    int* cnt    = (int*)(Wtf + DD * DD);              // N
    int* rowptr = cnt + N;                            // N+1
    int* bsums  = rowptr + N + 1;                     // 512
    int2* ev    = (int2*)(((uintptr_t)(bsums + 512) + 15) & ~(uintptr_t)15);  // E

    int nb = (N + 255) / 256;

    // CSR build (shared by both layers)
    hipMemsetAsync(cnt, 0, (size_t)N * sizeof(int), stream);
    k_hist<<<(E + 255) / 256, 256, 0, stream>>>(dst, cnt, E, N);
    k_scan_block<<<nb, 256, 0, stream>>>(cnt, rowptr, bsums, N);
    k_scan_bsums<<<1, 256, 0, stream>>>(bsums, nb);
    k_scan_add<<<nb, 256, 0, stream>>>(rowptr, bsums, cnt, dinv, N);
    hipMemsetAsync(cnt, 0, (size_t)N * sizeof(int), stream);
    k_fill<<<(E + 255) / 256, 256, 0, stream>>>(src, dst, rowptr, cnt, dinv, ev, E, N);

    // weight prep
    k_fuse_w<<<((DD + 1) * DD + 255) / 256, 256, 0, stream>>>(Wv, Wo, bv, bo, Wtf, bf);
    k_prep<<<64, 256, 0, stream>>>(W1, Wt1);
    k_prep<<<64, 256, 0, stream>>>(W2, Wt2);

    // layer 1
    k_gemm_mfma<1, 0><<<512, 256, 0, stream>>>(x, Wt1, nullptr, hA, N);
    k_gather_bf<<<2048, 256, 0, stream>>>(rowptr, ev, hA, dinv, b1, hB, N, 1);

    // layer 2
    k_gemm_mfma<0, 0><<<512, 256, 0, stream>>>(hB, Wt2, nullptr, hA, N);
    k_gather_bf<<<2048, 256, 0, stream>>>(rowptr, ev, hA, dinv, b2, hB, N, 0);

    // folded MHA
    k_gemm_mfma<0, 1><<<512, 256, 0, stream>>>(hB, Wtf, bf, out, N);
}